// Round 14
// baseline (282.630 us; speedup 1.0000x reference)
//
#include <hip/hip_runtime.h>
#include <hip/hip_bf16.h>

typedef __bf16 bf16x8 __attribute__((ext_vector_type(8)));
typedef float f32x4 __attribute__((ext_vector_type(4)));
typedef unsigned u32x2 __attribute__((ext_vector_type(2)));
typedef unsigned u32x4 __attribute__((ext_vector_type(4)));

#define LR_SLOPE 0.2f
#define NBKMAX 256          // buckets of 512 nodes -> supports N <= 131072
#define BCAP   12288        // per-bucket capacity (mean load 8704; overflow impossible)

static __device__ __forceinline__ unsigned short f2bf(float f){
  union { float f; unsigned u; } v; v.f = f;
  unsigned u = v.u;
  u += 0x7fffu + ((u >> 16) & 1u);
  return (unsigned short)(u >> 16);
}
static __device__ __forceinline__ float bf2f(unsigned short us){
  union { unsigned u; float f; } v; v.u = ((unsigned)us) << 16;
  return v.f;
}
static __device__ __forceinline__ unsigned pk2(float a, float b){
  return (unsigned)f2bf(a) | ((unsigned)f2bf(b) << 16);
}
// OCP e4m3 via gfx950 HW converts
static __device__ __forceinline__ unsigned char f2e4m3(float f){
  return (unsigned char)(__builtin_amdgcn_cvt_pk_fp8_f32(f, 0.f, 0, false) & 0xff);
}
static __device__ __forceinline__ float e4m32f(unsigned b){
  return __builtin_amdgcn_cvt_f32_fp8(b, 0);
}
typedef float f32x4v __attribute__((ext_vector_type(4)));
static __device__ __forceinline__ f32x4v ntl4(const float* p){
  return __builtin_nontemporal_load((const f32x4v*)p);
}

// ---------------- weight prep (merged) + bcnt zero ----------------
__global__ void prep_w_kernel(const float* __restrict__ W1, const float* __restrict__ W2,
                              unsigned short* __restrict__ wt1, unsigned short* __restrict__ wt2,
                              int* __restrict__ bcnt){
  int t = blockIdx.x*256 + threadIdx.x;
  if (t < 512*64){
    int k = t >> 6, n = t & 63;
    wt1[n*512 + k] = f2bf(W1[t]);
  } else if (t < 512*64 + 48*64){
    int t2 = t - 512*64;
    int c = t2 >> 6, k = t2 & 63;
    wt2[t2] = (c < 40) ? f2bf(W2[k*40 + c]) : (unsigned short)0;
  } else {
    int t3 = t - (512*64 + 48*64);
    if (t3 < NBKMAX) bcnt[t3] = 0;
  }
}

// ---------------- GEMM1 + fused attn1 ----------------
__global__ __launch_bounds__(256) void gemm1_kernel(
    const float* __restrict__ x, const unsigned short* __restrict__ wt1,
    const float* __restrict__ aw_s, const float* __restrict__ aw_d,
    unsigned char* __restrict__ h1p,
    unsigned short* __restrict__ as1p, float* __restrict__ ad1, int N)
{
  __shared__ unsigned short Alds[64*72];
  const int tid = threadIdx.x;
  const int wv = tid >> 6, lane = tid & 63;
  const int c0 = lane & 15, g = lane >> 4;
  const int rowbase = blockIdx.x * 64;

  const int sr = tid >> 2, sq = tid & 3;
  const int grow = rowbase + sr;
  const bool rv = grow < N;
  const float* xp = x + (size_t)grow*512 + sq*16;
  unsigned short* wls = Alds + sr*72 + sq*16;

  f32x4 acc[4];
  acc[0] = acc[1] = acc[2] = acc[3] = (f32x4){0.f,0.f,0.f,0.f};

  const unsigned short* bp0 = wt1 + (size_t)(wv*16 + c0)*512 + g*8;

  for (int kt = 0; kt < 8; ++kt){
    f32x4v f0 = {0,0,0,0}, f1 = {0,0,0,0}, f2 = {0,0,0,0}, f3 = {0,0,0,0};
    if (rv){
      const float* p = xp + kt*64;
      f0 = ntl4(p); f1 = ntl4(p+4); f2 = ntl4(p+8); f3 = ntl4(p+12);
    }
    u32x4 w0 = { pk2(f0.x,f0.y), pk2(f0.z,f0.w), pk2(f1.x,f1.y), pk2(f1.z,f1.w) };
    u32x4 w1 = { pk2(f2.x,f2.y), pk2(f2.z,f2.w), pk2(f3.x,f3.y), pk2(f3.z,f3.w) };
    if (kt) __syncthreads();
    *(u32x4*)wls       = w0;
    *(u32x4*)(wls + 8) = w1;
    __syncthreads();
    bf16x8 b0 = *(const bf16x8*)(bp0 + kt*64);
    bf16x8 b1 = *(const bf16x8*)(bp0 + kt*64 + 32);
    #pragma unroll
    for (int mi = 0; mi < 4; ++mi){
      const unsigned short* ap = Alds + (mi*16 + c0)*72 + g*8;
      bf16x8 a0 = *(const bf16x8*)ap;
      bf16x8 a1 = *(const bf16x8*)(ap + 32);
      acc[mi] = __builtin_amdgcn_mfma_f32_16x16x32_bf16(a0, b0, acc[mi], 0,0,0);
      acc[mi] = __builtin_amdgcn_mfma_f32_16x16x32_bf16(a1, b1, acc[mi], 0,0,0);
    }
  }
  // epilogue: fp8 store + fused attention dots (wave wv owns heads 2wv, 2wv+1)
  const int hh = wv*2 + (c0 >> 3);
  const float aws_l = aw_s[hh*8 + (c0 & 7)];
  const float awd_l = aw_d[hh*8 + (c0 & 7)];
  #pragma unroll
  for (int mi = 0; mi < 4; ++mi){
    #pragma unroll
    for (int i = 0; i < 4; ++i){
      int row = rowbase + mi*16 + 4*g + i;
      float av = acc[mi][i];
      if (row < N) h1p[(size_t)row*64 + wv*16 + c0] = f2e4m3(av);
      float ss = av * aws_l;
      float dd = av * awd_l;
      ss += __shfl_xor(ss, 1); ss += __shfl_xor(ss, 2); ss += __shfl_xor(ss, 4);
      dd += __shfl_xor(dd, 1); dd += __shfl_xor(dd, 2); dd += __shfl_xor(dd, 4);
      if (row < N && (c0 & 7) == 0){
        as1p[row*8 + hh] = f2bf(ss);
        ad1[row*8 + hh]  = dd;
      }
    }
  }
}

// ---------------- bucket phase A: single ei pass, fixed-capacity buckets ----------------
__global__ __launch_bounds__(256) void bucketA_kernel(
    const int* __restrict__ ei, int* __restrict__ bcnt,
    unsigned* __restrict__ bucketed, int E, int M, int NBK)
{
  __shared__ int hist[NBKMAX];
  __shared__ int gb[NBKMAX];
  const int tid = threadIdx.x;
  const int t0 = blockIdx.x * 2048;
  for (int i = tid; i < NBK; i += 256) hist[i] = 0;
  __syncthreads();

  unsigned pe[8]; int bk[8], rnk[8];
  #pragma unroll
  for (int j = 0; j < 8; ++j){
    int m = t0 + j*256 + tid;
    if (m < M){
      int s, d;
      if (m < E){ s = ei[m]; d = ei[E + m]; }
      else      { s = d = m - E; }
      bk[j] = d >> 9;
      pe[j] = ((unsigned)s << 9) | (unsigned)(d & 511);
      rnk[j] = atomicAdd(&hist[bk[j]], 1);
    } else bk[j] = -1;
  }
  __syncthreads();
  for (int i = tid; i < NBK; i += 256) gb[i] = atomicAdd(&bcnt[i], hist[i]);
  __syncthreads();
  #pragma unroll
  for (int j = 0; j < 8; ++j){
    if (bk[j] >= 0) bucketed[(size_t)bk[j]*BCAP + gb[bk[j]] + rnk[j]] = pe[j];
  }
}

// ---------------- bucket phase B: inline bucket scan + LDS counting sort ----------------
__global__ __launch_bounds__(512) void bucketB_kernel(
    const unsigned* __restrict__ bucketed, const int* __restrict__ bcnt,
    int* __restrict__ rowstart, int* __restrict__ csr, int N, int M, int NBK)
{
  __shared__ int cnt[512];
  __shared__ int cur[512];
  __shared__ int basevar;
  const int k = blockIdx.x;
  const int nodebase = k << 9;
  const int nn = min(512, N - nodebase);
  const int t = threadIdx.x;

  // inline exclusive scan over bucket counts to get this bucket's base
  cur[t] = (t < NBK) ? bcnt[t] : 0;
  __syncthreads();
  for (int off = 1; off < 256; off <<= 1){
    int u = (t >= off && t < 256) ? cur[t-off] : 0;
    __syncthreads();
    if (t < 256) cur[t] += u;
    __syncthreads();
  }
  if (t == 0) basevar = (k > 0) ? cur[k-1] : 0;
  cnt[t] = 0;
  __syncthreads();

  const int ck = bcnt[k];
  const unsigned* bp = bucketed + (size_t)k*BCAP;
  for (int m = t; m < ck; m += 512) atomicAdd(&cnt[bp[m] & 511], 1);
  __syncthreads();
  int myc = cnt[t];
  cur[t] = myc; __syncthreads();
  for (int off = 1; off < 512; off <<= 1){
    int u = (t >= off) ? cur[t-off] : 0;
    __syncthreads();
    cur[t] += u;
    __syncthreads();
  }
  const int base = basevar;
  int excl = base + cur[t] - myc;
  if (t < nn) rowstart[nodebase + t] = excl;
  if (k == 0 && t == 0) rowstart[N] = M;
  cnt[t] = excl;
  __syncthreads();
  for (int m = t; m < ck; m += 512){
    unsigned e = bp[m];
    int pos = atomicAdd(&cnt[e & 511], 1);
    csr[pos] = (int)(e >> 9);
  }
}

// ---------------- layer-1 aggregation + fused GEMM2 + attn2 ----------------
// Produces packed h2x row = [f32 as2 | 40 fp8 h2 | pad] (stride 64) + ad2 directly.
__global__ __launch_bounds__(256) void l1agg_kernel(
    const int* __restrict__ rowstart, const int* __restrict__ csr,
    const unsigned short* __restrict__ as1p,   // bf16 [N][8]
    const float* __restrict__ ad1,             // f32 [N][8]
    const unsigned char* __restrict__ h1p,     // fp8 [N][64]
    const float* __restrict__ b1,
    const unsigned short* __restrict__ wt2,    // bf16 [48][64] (c-major)
    const float* __restrict__ aw_s2, const float* __restrict__ aw_d2,
    unsigned char* __restrict__ h2x, float* __restrict__ ad2, int N)
{
  __shared__ unsigned w2l[32*40];              // [k2][c]: bf16 pair (W2[2k2][c], W2[2k2+1][c])
  __shared__ float g1buf[4][64];
  const int tid = threadIdx.x;
  for (int idx = tid; idx < 40*32; idx += 256){
    int c = idx >> 5, k2 = idx & 31;
    unsigned lo = wt2[c*64 + 2*k2];
    unsigned hi = wt2[c*64 + 2*k2 + 1];
    w2l[k2*40 + c] = lo | (hi << 16);
  }
  __syncthreads();

  const int wvid = tid >> 6;
  int wid = blockIdx.x*4 + wvid;
  if (wid >= N) return;
  const int lane = tid & 63;
  const int jq  = lane >> 3;          // weight role: edge-in-chunk 0..7
  const int hq  = lane & 7;           // weight role: head 0..7
  const int par = lane >> 4;          // feature role: edge-in-quad 0..3
  const int q   = lane & 15;          // feature role: u32 idx (feats 4q..4q+3)
  const int hh  = q >> 1;             // head of this u32
  int r0 = rowstart[wid], r1 = rowstart[wid+1];
  int cnt = r1 - r0;
  int cap = cnt < 64 ? cnt : 64;
  int myidx = csr[r0 + (lane < cap ? lane : cap-1)];
  const float advq = ad1[wid*8 + hq];

  float a0 = 0.f, a1 = 0.f, a2 = 0.f, a3 = 0.f, den = 0.f;
  for (int c = 0; c < cap; c += 8){
    int se = __shfl(myidx, c + jq);
    float t = bf2f(as1p[se*8 + hq]) + advq;
    t = (t > 0.f) ? t : LR_SLOPE*t;
    float w = __expf(t);
    if (c + jq >= cap) w = 0.f;
    den += w;
    #pragma unroll
    for (int j = 0; j < 2; ++j){
      int s8 = 4*j + par;
      int sj = __shfl(myidx, c + s8);
      float wj = __shfl(w, s8*8 + hh);
      unsigned hv = *(const unsigned*)(h1p + (size_t)sj*64 + 4*q);
      a0 = fmaf(wj, __builtin_amdgcn_cvt_f32_fp8(hv, 0), a0);
      a1 = fmaf(wj, __builtin_amdgcn_cvt_f32_fp8(hv, 1), a1);
      a2 = fmaf(wj, __builtin_amdgcn_cvt_f32_fp8(hv, 2), a2);
      a3 = fmaf(wj, __builtin_amdgcn_cvt_f32_fp8(hv, 3), a3);
    }
  }
  for (int r = r0 + 64; r < r1; ++r){            // degree>64 fallback (rare)
    int sx = csr[r];
    float t = bf2f(as1p[sx*8 + hq]) + advq;
    t = (t > 0.f) ? t : LR_SLOPE*t;
    float w = __expf(t);
    if (lane < 8) den += w;                      // one copy per head
    float wj = __shfl(w, hh);
    if (par == 0){
      unsigned hv = *(const unsigned*)(h1p + (size_t)sx*64 + 4*q);
      a0 = fmaf(wj, __builtin_amdgcn_cvt_f32_fp8(hv, 0), a0);
      a1 = fmaf(wj, __builtin_amdgcn_cvt_f32_fp8(hv, 1), a1);
      a2 = fmaf(wj, __builtin_amdgcn_cvt_f32_fp8(hv, 2), a2);
      a3 = fmaf(wj, __builtin_amdgcn_cvt_f32_fp8(hv, 3), a3);
    }
  }
  den += __shfl_xor(den, 8); den += __shfl_xor(den, 16); den += __shfl_xor(den, 32);
  a0 += __shfl_xor(a0, 16); a0 += __shfl_xor(a0, 32);
  a1 += __shfl_xor(a1, 16); a1 += __shfl_xor(a1, 32);
  a2 += __shfl_xor(a2, 16); a2 += __shfl_xor(a2, 32);
  a3 += __shfl_xor(a3, 16); a3 += __shfl_xor(a3, 32);
  if (lane < 16){
    float rdv = 1.f / __shfl(den, hh);
    float v0 = fmaf(a0, rdv, b1[4*q]);
    float v1 = fmaf(a1, rdv, b1[4*q + 1]);
    float v2 = fmaf(a2, rdv, b1[4*q + 2]);
    float v3 = fmaf(a3, rdv, b1[4*q + 3]);
    v0 = (v0 > 0.f) ? v0 : (__expf(v0) - 1.f);   // ELU fused
    v1 = (v1 > 0.f) ? v1 : (__expf(v1) - 1.f);
    v2 = (v2 > 0.f) ? v2 : (__expf(v2) - 1.f);
    v3 = (v3 > 0.f) ? v3 : (__expf(v3) - 1.f);
    *(f32x4*)&g1buf[wvid][4*q] = (f32x4){v0, v1, v2, v3};
  }
  __asm__ volatile("s_waitcnt lgkmcnt(0)" ::: "memory");

  // fused GEMM2: h2[c] = sum_k g1[k] * W2[k][c], c = lane (cols 0..39)
  const int cc = (lane < 40) ? lane : 0;
  const float* gb = g1buf[wvid];
  float hc = 0.f;
  #pragma unroll
  for (int k2 = 0; k2 < 32; ++k2){
    float ga = gb[2*k2];                          // broadcast LDS reads
    float gbv = gb[2*k2 + 1];
    unsigned wp = w2l[k2*40 + cc];
    hc = fmaf(ga,  bf2f((unsigned short)(wp & 0xffff)),
         fmaf(gbv, bf2f((unsigned short)(wp >> 16)), hc));
  }
  // fused attn2 reduction
  float ss = (lane < 40) ? hc * aw_s2[cc] : 0.f;
  float dd = (lane < 40) ? hc * aw_d2[cc] : 0.f;
  #pragma unroll
  for (int off = 32; off; off >>= 1){ ss += __shfl_xor(ss, off); dd += __shfl_xor(dd, off); }
  if (lane == 0){
    *(float*)(h2x + (size_t)wid*64) = ss;
    ad2[wid] = dd;
  }
  if (lane < 40) h2x[(size_t)wid*64 + 4 + lane] = f2e4m3(hc);
}

// ---------------- layer-2 aggregation: 1 request/edge (packed row) + log_softmax ----------------
// lane groups of 11: il=0 reads as2 (f32), il=1..10 read u32 of 4 fp8 feats; 5 edges/iter.
__global__ __launch_bounds__(256) void l2agg_kernel(
    const int* __restrict__ rowstart, const int* __restrict__ csr,
    const unsigned char* __restrict__ h2x, const float* __restrict__ ad2,
    const float* __restrict__ b2, float* __restrict__ out, int N)
{
  int wid = blockIdx.x*4 + (threadIdx.x >> 6);
  if (wid >= N) return;
  const int lane = threadIdx.x & 63;
  const int eg = lane / 11;             // edge group 0..4 (5 = idle lanes 55-63)
  const int il = lane - eg*11;          // 0 = weight lane, 1..10 = feature u32s
  const bool valid = eg < 5;
  int r0 = rowstart[wid], r1 = rowstart[wid+1];
  int cnt = r1 - r0;
  int cap = cnt < 64 ? cnt : 64;
  int myidx = csr[r0 + (lane < cap ? lane : cap-1)];
  const float adv = ad2[wid];

  float a0 = 0.f, a1 = 0.f, a2 = 0.f, a3 = 0.f, den = 0.f;
  for (int c = 0; c < cap; c += 5){
    int slot = c + eg;
    int slc  = slot < cap ? slot : cap-1;
    int sj = __shfl(myidx, slc);
    unsigned hv = valid ? *(const unsigned*)(h2x + (size_t)sj*64 + 4*il) : 0u;
    union { unsigned u; float f; } cv; cv.u = hv;
    float t = cv.f + adv;
    t = (t > 0.f) ? t : LR_SLOPE*t;
    float w = __expf(t);
    if (slot >= cap || !valid) w = 0.f;
    if (il == 0) den += w;
    float wj = __shfl(w, eg*11);        // broadcast group's weight
    a0 = fmaf(wj, __builtin_amdgcn_cvt_f32_fp8(hv, 0), a0);
    a1 = fmaf(wj, __builtin_amdgcn_cvt_f32_fp8(hv, 1), a1);
    a2 = fmaf(wj, __builtin_amdgcn_cvt_f32_fp8(hv, 2), a2);
    a3 = fmaf(wj, __builtin_amdgcn_cvt_f32_fp8(hv, 3), a3);
  }
  for (int r = r0 + 64; r < r1; ++r){   // degree>64 fallback (rare)
    int sx = csr[r];
    unsigned hv = valid ? *(const unsigned*)(h2x + (size_t)sx*64 + 4*il) : 0u;
    union { unsigned u; float f; } cv; cv.u = hv;
    float t = cv.f + adv;
    t = (t > 0.f) ? t : LR_SLOPE*t;
    float w = __expf(t);
    float wj = __shfl(w, 0);            // lane 0 (eg0,il0) holds the weight
    if (lane == 0) den += wj;
    if (eg == 0){
      a0 = fmaf(wj, __builtin_amdgcn_cvt_f32_fp8(hv, 0), a0);
      a1 = fmaf(wj, __builtin_amdgcn_cvt_f32_fp8(hv, 1), a1);
      a2 = fmaf(wj, __builtin_amdgcn_cvt_f32_fp8(hv, 2), a2);
      a3 = fmaf(wj, __builtin_amdgcn_cvt_f32_fp8(hv, 3), a3);
    }
  }
  // den: only il==0 lanes hold contributions; full-wave xor reduce sums them
  #pragma unroll
  for (int off = 32; off; off >>= 1) den += __shfl_xor(den, off);
  // combine the 5 edge groups per feature position
  float t0 = a0, t1 = a1, t2 = a2, t3 = a3;
  #pragma unroll
  for (int gix = 1; gix < 5; ++gix){
    int src = ((eg + gix) % 5)*11 + il;
    t0 += __shfl(a0, src);
    t1 += __shfl(a1, src);
    t2 += __shfl(a2, src);
    t3 += __shfl(a3, src);
  }
  const bool outl = (eg == 0) && (il >= 1);      // lanes 1..10 own feats 4(il-1)..
  const int fb = (il - 1)*4;
  float rdv = 1.f/den;
  float v0 = outl ? fmaf(t0, rdv, b2[fb])     : -1e30f;
  float v1 = outl ? fmaf(t1, rdv, b2[fb + 1]) : -1e30f;
  float v2 = outl ? fmaf(t2, rdv, b2[fb + 2]) : -1e30f;
  float v3 = outl ? fmaf(t3, rdv, b2[fb + 3]) : -1e30f;
  // log_softmax over the 40 features
  float m = fmaxf(fmaxf(v0, v1), fmaxf(v2, v3));
  #pragma unroll
  for (int off = 32; off; off >>= 1) m = fmaxf(m, __shfl_xor(m, off));
  float sum = outl ? (__expf(v0-m) + __expf(v1-m) + __expf(v2-m) + __expf(v3-m)) : 0.f;
  #pragma unroll
  for (int off = 32; off; off >>= 1) sum += __shfl_xor(sum, off);
  if (outl){
    float ls = m + __logf(sum);
    f32x4 o = { v0 - ls, v1 - ls, v2 - ls, v3 - ls };
    *(f32x4*)(out + (size_t)wid*40 + fb) = o;
  }
}

// ---------------- host ----------------
extern "C" void kernel_launch(void* const* d_in, const int* in_sizes, int n_in,
                              void* d_out, int out_size, void* d_ws, size_t ws_size,
                              hipStream_t stream)
{
  const float* x   = (const float*)d_in[0];
  const int*   ei  = (const int*)d_in[1];
  const float* W1  = (const float*)d_in[2];
  const float* aS1 = (const float*)d_in[3];
  const float* aD1 = (const float*)d_in[4];
  const float* b1  = (const float*)d_in[5];
  const float* W2  = (const float*)d_in[6];
  const float* aS2 = (const float*)d_in[7];
  const float* aD2 = (const float*)d_in[8];
  const float* b2  = (const float*)d_in[9];

  const int N   = in_sizes[0] / 512;
  const int E   = in_sizes[1] / 2;
  const int M   = E + N;
  const int NBK = (N + 511) >> 9;

  char* base = (char*)d_ws;
  size_t off = 0;
  auto alloc = [&](size_t bytes)->char* {
    char* p = base + off;
    off += (bytes + 255) & ~(size_t)255;
    return p;
  };
  unsigned char*  h1p  = (unsigned char*)alloc((size_t)N*64);   // fp8 [N][64]
  unsigned char*  h2x  = (unsigned char*)alloc((size_t)N*64);   // [f32 as2 | 40 fp8 | pad]
  unsigned short* as1p = (unsigned short*)alloc((size_t)N*8*2); // bf16 [N][8]
  float* ad1      = (float*)alloc((size_t)N*8*4);
  float* ad2      = (float*)alloc((size_t)N*4);
  int*   rowstart = (int*)alloc((size_t)(N+1)*4);
  int*   bcnt     = (int*)alloc((size_t)NBKMAX*4);
  int*   csr      = (int*)alloc((size_t)M*4);
  unsigned* bucketed = (unsigned*)alloc((size_t)NBKMAX*BCAP*4); // 12 MB
  unsigned short* wt1 = (unsigned short*)alloc(64*512*2);
  unsigned short* wt2 = (unsigned short*)alloc(48*64*2);
  float* outp = (float*)d_out;

  prep_w_kernel<<<141, 256, 0, stream>>>(W1, W2, wt1, wt2, bcnt);
  gemm1_kernel<<<(N+63)/64, 256, 0, stream>>>(x, wt1, aS1, aD1, h1p, as1p, ad1, N);
  bucketA_kernel<<<(M+2047)/2048, 256, 0, stream>>>(ei, bcnt, bucketed, E, M, NBK);
  bucketB_kernel<<<NBK, 512, 0, stream>>>(bucketed, bcnt, rowstart, csr, N, M, NBK);
  l1agg_kernel<<<(N+3)/4, 256, 0, stream>>>(rowstart, csr, as1p, ad1, h1p, b1,
                                            wt2, aS2, aD2, h2x, ad2, N);
  l2agg_kernel<<<(N+3)/4, 256, 0, stream>>>(rowstart, csr, h2x, ad2, b2, outp, N);
}

// Round 15
// 252.517 us; speedup vs baseline: 1.1192x; 1.1192x over previous
//
#include <hip/hip_runtime.h>
#include <hip/hip_bf16.h>

typedef __bf16 bf16x8 __attribute__((ext_vector_type(8)));
typedef float f32x4 __attribute__((ext_vector_type(4)));
typedef unsigned u32x2 __attribute__((ext_vector_type(2)));
typedef unsigned u32x4 __attribute__((ext_vector_type(4)));

#define LR_SLOPE 0.2f
#define NBKMAX 256          // buckets of 512 nodes -> supports N <= 131072
#define BCAP   12288        // per-bucket capacity (mean load 8704; overflow impossible)

static __device__ __forceinline__ unsigned short f2bf(float f){
  union { float f; unsigned u; } v; v.f = f;
  unsigned u = v.u;
  u += 0x7fffu + ((u >> 16) & 1u);
  return (unsigned short)(u >> 16);
}
static __device__ __forceinline__ float bf2f(unsigned short us){
  union { unsigned u; float f; } v; v.u = ((unsigned)us) << 16;
  return v.f;
}
static __device__ __forceinline__ unsigned pk2(float a, float b){
  return (unsigned)f2bf(a) | ((unsigned)f2bf(b) << 16);
}
// OCP e4m3 via gfx950 HW converts
static __device__ __forceinline__ unsigned char f2e4m3(float f){
  return (unsigned char)(__builtin_amdgcn_cvt_pk_fp8_f32(f, 0.f, 0, false) & 0xff);
}
static __device__ __forceinline__ float e4m32f(unsigned b){
  return __builtin_amdgcn_cvt_f32_fp8(b, 0);
}
typedef float f32x4v __attribute__((ext_vector_type(4)));
static __device__ __forceinline__ f32x4v ntl4(const float* p){
  return __builtin_nontemporal_load((const f32x4v*)p);
}

// ---------------- weight prep (merged) + bcnt zero ----------------
__global__ void prep_w_kernel(const float* __restrict__ W1, const float* __restrict__ W2,
                              unsigned short* __restrict__ wt1, unsigned short* __restrict__ wt2,
                              int* __restrict__ bcnt){
  int t = blockIdx.x*256 + threadIdx.x;
  if (t < 512*64){
    int k = t >> 6, n = t & 63;
    wt1[n*512 + k] = f2bf(W1[t]);
  } else if (t < 512*64 + 48*64){
    int t2 = t - 512*64;
    int c = t2 >> 6, k = t2 & 63;
    wt2[t2] = (c < 40) ? f2bf(W2[k*40 + c]) : (unsigned short)0;
  } else {
    int t3 = t - (512*64 + 48*64);
    if (t3 < NBKMAX) bcnt[t3] = 0;
  }
}

// ---------------- GEMM1 + fused attn1 ----------------
__global__ __launch_bounds__(256) void gemm1_kernel(
    const float* __restrict__ x, const unsigned short* __restrict__ wt1,
    const float* __restrict__ aw_s, const float* __restrict__ aw_d,
    unsigned char* __restrict__ h1p,
    unsigned short* __restrict__ as1p, float* __restrict__ ad1, int N)
{
  __shared__ unsigned short Alds[64*72];
  const int tid = threadIdx.x;
  const int wv = tid >> 6, lane = tid & 63;
  const int c0 = lane & 15, g = lane >> 4;
  const int rowbase = blockIdx.x * 64;

  const int sr = tid >> 2, sq = tid & 3;
  const int grow = rowbase + sr;
  const bool rv = grow < N;
  const float* xp = x + (size_t)grow*512 + sq*16;
  unsigned short* wls = Alds + sr*72 + sq*16;

  f32x4 acc[4];
  acc[0] = acc[1] = acc[2] = acc[3] = (f32x4){0.f,0.f,0.f,0.f};

  const unsigned short* bp0 = wt1 + (size_t)(wv*16 + c0)*512 + g*8;

  for (int kt = 0; kt < 8; ++kt){
    f32x4v f0 = {0,0,0,0}, f1 = {0,0,0,0}, f2 = {0,0,0,0}, f3 = {0,0,0,0};
    if (rv){
      const float* p = xp + kt*64;
      f0 = ntl4(p); f1 = ntl4(p+4); f2 = ntl4(p+8); f3 = ntl4(p+12);
    }
    u32x4 w0 = { pk2(f0.x,f0.y), pk2(f0.z,f0.w), pk2(f1.x,f1.y), pk2(f1.z,f1.w) };
    u32x4 w1 = { pk2(f2.x,f2.y), pk2(f2.z,f2.w), pk2(f3.x,f3.y), pk2(f3.z,f3.w) };
    if (kt) __syncthreads();
    *(u32x4*)wls       = w0;
    *(u32x4*)(wls + 8) = w1;
    __syncthreads();
    bf16x8 b0 = *(const bf16x8*)(bp0 + kt*64);
    bf16x8 b1 = *(const bf16x8*)(bp0 + kt*64 + 32);
    #pragma unroll
    for (int mi = 0; mi < 4; ++mi){
      const unsigned short* ap = Alds + (mi*16 + c0)*72 + g*8;
      bf16x8 a0 = *(const bf16x8*)ap;
      bf16x8 a1 = *(const bf16x8*)(ap + 32);
      acc[mi] = __builtin_amdgcn_mfma_f32_16x16x32_bf16(a0, b0, acc[mi], 0,0,0);
      acc[mi] = __builtin_amdgcn_mfma_f32_16x16x32_bf16(a1, b1, acc[mi], 0,0,0);
    }
  }
  // epilogue: fp8 store + fused attention dots (wave wv owns heads 2wv, 2wv+1)
  const int hh = wv*2 + (c0 >> 3);
  const float aws_l = aw_s[hh*8 + (c0 & 7)];
  const float awd_l = aw_d[hh*8 + (c0 & 7)];
  #pragma unroll
  for (int mi = 0; mi < 4; ++mi){
    #pragma unroll
    for (int i = 0; i < 4; ++i){
      int row = rowbase + mi*16 + 4*g + i;
      float av = acc[mi][i];
      if (row < N) h1p[(size_t)row*64 + wv*16 + c0] = f2e4m3(av);
      float ss = av * aws_l;
      float dd = av * awd_l;
      ss += __shfl_xor(ss, 1); ss += __shfl_xor(ss, 2); ss += __shfl_xor(ss, 4);
      dd += __shfl_xor(dd, 1); dd += __shfl_xor(dd, 2); dd += __shfl_xor(dd, 4);
      if (row < N && (c0 & 7) == 0){
        as1p[row*8 + hh] = f2bf(ss);
        ad1[row*8 + hh]  = dd;
      }
    }
  }
}

// ---------------- bucket phase A: single ei pass, fixed-capacity buckets ----------------
__global__ __launch_bounds__(256) void bucketA_kernel(
    const int* __restrict__ ei, int* __restrict__ bcnt,
    unsigned* __restrict__ bucketed, int E, int M, int NBK)
{
  __shared__ int hist[NBKMAX];
  __shared__ int gb[NBKMAX];
  const int tid = threadIdx.x;
  const int t0 = blockIdx.x * 2048;
  for (int i = tid; i < NBK; i += 256) hist[i] = 0;
  __syncthreads();

  unsigned pe[8]; int bk[8], rnk[8];
  #pragma unroll
  for (int j = 0; j < 8; ++j){
    int m = t0 + j*256 + tid;
    if (m < M){
      int s, d;
      if (m < E){ s = ei[m]; d = ei[E + m]; }
      else      { s = d = m - E; }
      bk[j] = d >> 9;
      pe[j] = ((unsigned)s << 9) | (unsigned)(d & 511);
      rnk[j] = atomicAdd(&hist[bk[j]], 1);
    } else bk[j] = -1;
  }
  __syncthreads();
  for (int i = tid; i < NBK; i += 256) gb[i] = atomicAdd(&bcnt[i], hist[i]);
  __syncthreads();
  #pragma unroll
  for (int j = 0; j < 8; ++j){
    if (bk[j] >= 0) bucketed[(size_t)bk[j]*BCAP + gb[bk[j]] + rnk[j]] = pe[j];
  }
}

// ---------------- bucket phase B: inline bucket scan + LDS counting sort ----------------
__global__ __launch_bounds__(512) void bucketB_kernel(
    const unsigned* __restrict__ bucketed, const int* __restrict__ bcnt,
    int* __restrict__ rowstart, int* __restrict__ csr, int N, int M, int NBK)
{
  __shared__ int cnt[512];
  __shared__ int cur[512];
  __shared__ int basevar;
  const int k = blockIdx.x;
  const int nodebase = k << 9;
  const int nn = min(512, N - nodebase);
  const int t = threadIdx.x;

  cur[t] = (t < NBK) ? bcnt[t] : 0;
  __syncthreads();
  for (int off = 1; off < 256; off <<= 1){
    int u = (t >= off && t < 256) ? cur[t-off] : 0;
    __syncthreads();
    if (t < 256) cur[t] += u;
    __syncthreads();
  }
  if (t == 0) basevar = (k > 0) ? cur[k-1] : 0;
  cnt[t] = 0;
  __syncthreads();

  const int ck = bcnt[k];
  const unsigned* bp = bucketed + (size_t)k*BCAP;
  for (int m = t; m < ck; m += 512) atomicAdd(&cnt[bp[m] & 511], 1);
  __syncthreads();
  int myc = cnt[t];
  cur[t] = myc; __syncthreads();
  for (int off = 1; off < 512; off <<= 1){
    int u = (t >= off) ? cur[t-off] : 0;
    __syncthreads();
    cur[t] += u;
    __syncthreads();
  }
  const int base = basevar;
  int excl = base + cur[t] - myc;
  if (t < nn) rowstart[nodebase + t] = excl;
  if (k == 0 && t == 0) rowstart[N] = M;
  cnt[t] = excl;
  __syncthreads();
  for (int m = t; m < ck; m += 512){
    unsigned e = bp[m];
    int pos = atomicAdd(&cnt[e & 511], 1);
    csr[pos] = (int)(e >> 9);
  }
}

// ---------------- layer-1 aggregation: prefetch-all (max MLP) ----------------
__global__ __launch_bounds__(256) void l1agg_kernel(
    const int* __restrict__ rowstart, const int* __restrict__ csr,
    const unsigned short* __restrict__ as1p,   // bf16 [N][8]
    const float* __restrict__ ad1,             // f32 [N][8]
    const unsigned char* __restrict__ h1p,     // fp8 [N][64]
    const float* __restrict__ b1,
    unsigned short* __restrict__ g1b, int N)
{
  int wid = blockIdx.x*4 + (threadIdx.x >> 6);
  if (wid >= N) return;
  const int lane = threadIdx.x & 63;
  const int jq  = lane >> 3;          // weight role: edge-in-chunk 0..7
  const int hq  = lane & 7;           // weight role: head 0..7
  const int par = lane >> 4;          // feature role: edge-in-quad 0..3
  const int q   = lane & 15;          // feature role: u32 idx (feats 4q..4q+3)
  const int hh  = q >> 1;             // head of this u32
  int r0 = rowstart[wid], r1 = rowstart[wid+1];
  int cnt = r1 - r0;
  int cap = cnt < 64 ? cnt : 64;
  int myidx = csr[r0 + (lane < cap ? lane : cap-1)];
  const float advq = ad1[wid*8 + hq];

  float a0 = 0.f, a1 = 0.f, a2 = 0.f, a3 = 0.f, den = 0.f;

  // phase A: issue ALL gathers (wave-uniform guards; clamped indices are valid)
#define L1LOAD(i) \
  unsigned short evu##i = 0; unsigned hvA##i = 0, hvB##i = 0; \
  if (8*i < cap){ \
    int se  = __shfl(myidx, 8*i + jq); \
    evu##i = as1p[se*8 + hq]; \
    int sjA = __shfl(myidx, 8*i + par); \
    int sjB = __shfl(myidx, 8*i + 4 + par); \
    hvA##i = *(const unsigned*)(h1p + (size_t)sjA*64 + 4*q); \
    hvB##i = *(const unsigned*)(h1p + (size_t)sjB*64 + 4*q); \
  }
  L1LOAD(0) L1LOAD(1) L1LOAD(2) L1LOAD(3)
  L1LOAD(4) L1LOAD(5) L1LOAD(6) L1LOAD(7)
#undef L1LOAD

  // phase B: consume in issue order
#define L1COMP(i) \
  if (8*i < cap){ \
    float t = bf2f(evu##i) + advq; \
    t = (t > 0.f) ? t : LR_SLOPE*t; \
    float w = __expf(t); \
    if (8*i + jq >= cap) w = 0.f; \
    den += w; \
    float wjA = __shfl(w, par*8 + hh); \
    float wjB = __shfl(w, (4 + par)*8 + hh); \
    a0 = fmaf(wjA, __builtin_amdgcn_cvt_f32_fp8(hvA##i, 0), a0); \
    a1 = fmaf(wjA, __builtin_amdgcn_cvt_f32_fp8(hvA##i, 1), a1); \
    a2 = fmaf(wjA, __builtin_amdgcn_cvt_f32_fp8(hvA##i, 2), a2); \
    a3 = fmaf(wjA, __builtin_amdgcn_cvt_f32_fp8(hvA##i, 3), a3); \
    a0 = fmaf(wjB, __builtin_amdgcn_cvt_f32_fp8(hvB##i, 0), a0); \
    a1 = fmaf(wjB, __builtin_amdgcn_cvt_f32_fp8(hvB##i, 1), a1); \
    a2 = fmaf(wjB, __builtin_amdgcn_cvt_f32_fp8(hvB##i, 2), a2); \
    a3 = fmaf(wjB, __builtin_amdgcn_cvt_f32_fp8(hvB##i, 3), a3); \
  }
  L1COMP(0) L1COMP(1) L1COMP(2) L1COMP(3)
  L1COMP(4) L1COMP(5) L1COMP(6) L1COMP(7)
#undef L1COMP

  for (int r = r0 + 64; r < r1; ++r){            // degree>64 fallback (rare)
    int sx = csr[r];
    float t = bf2f(as1p[sx*8 + hq]) + advq;
    t = (t > 0.f) ? t : LR_SLOPE*t;
    float w = __expf(t);
    if (lane < 8) den += w;                      // one copy per head
    float wj = __shfl(w, hh);
    if (par == 0){
      unsigned hv = *(const unsigned*)(h1p + (size_t)sx*64 + 4*q);
      a0 = fmaf(wj, __builtin_amdgcn_cvt_f32_fp8(hv, 0), a0);
      a1 = fmaf(wj, __builtin_amdgcn_cvt_f32_fp8(hv, 1), a1);
      a2 = fmaf(wj, __builtin_amdgcn_cvt_f32_fp8(hv, 2), a2);
      a3 = fmaf(wj, __builtin_amdgcn_cvt_f32_fp8(hv, 3), a3);
    }
  }
  den += __shfl_xor(den, 8); den += __shfl_xor(den, 16); den += __shfl_xor(den, 32);
  a0 += __shfl_xor(a0, 16); a0 += __shfl_xor(a0, 32);
  a1 += __shfl_xor(a1, 16); a1 += __shfl_xor(a1, 32);
  a2 += __shfl_xor(a2, 16); a2 += __shfl_xor(a2, 32);
  a3 += __shfl_xor(a3, 16); a3 += __shfl_xor(a3, 32);
  if (lane < 16){
    float rdv = 1.f / __shfl(den, hh);
    float v0 = fmaf(a0, rdv, b1[4*q]);
    float v1 = fmaf(a1, rdv, b1[4*q + 1]);
    float v2 = fmaf(a2, rdv, b1[4*q + 2]);
    float v3 = fmaf(a3, rdv, b1[4*q + 3]);
    v0 = (v0 > 0.f) ? v0 : (__expf(v0) - 1.f);   // ELU fused
    v1 = (v1 > 0.f) ? v1 : (__expf(v1) - 1.f);
    v2 = (v2 > 0.f) ? v2 : (__expf(v2) - 1.f);
    v3 = (v3 > 0.f) ? v3 : (__expf(v3) - 1.f);
    u32x2 pk = { pk2(v0, v1), pk2(v2, v3) };
    *(u32x2*)(g1b + (size_t)wid*64 + 4*q) = pk;
  }
}

// ---------------- GEMM2 + fused attn2: packed h2x row = [f32 as2 | 40 fp8], stride 64 ----------------
__global__ __launch_bounds__(256) void gemm2_kernel(
    const unsigned short* __restrict__ g1b, const unsigned short* __restrict__ wt2,
    const float* __restrict__ aw_s, const float* __restrict__ aw_d,
    unsigned char* __restrict__ h2x, float* __restrict__ ad2, int N)
{
  __shared__ unsigned short Alds[64*72];
  const int tid = threadIdx.x;
  const int wv = tid >> 6, lane = tid & 63;
  const int c0 = lane & 15, g = lane >> 4;
  const int rowbase = blockIdx.x * 64;

  const int sr = tid >> 2, sq = tid & 3;
  const int grow = rowbase + sr;
  const bool rv = grow < N;
  u32x4 w0 = {0,0,0,0}, w1 = {0,0,0,0};
  if (rv){
    const u32x4* gp = (const u32x4*)(g1b + (size_t)grow*64 + sq*16);
    w0 = gp[0];
    w1 = gp[1];
  }
  unsigned short* wls = Alds + sr*72 + sq*16;
  *(u32x4*)wls       = w0;
  *(u32x4*)(wls + 8) = w1;
  __syncthreads();

  f32x4 acc[3];
  acc[0] = acc[1] = acc[2] = (f32x4){0.f,0.f,0.f,0.f};
  #pragma unroll
  for (int t2 = 0; t2 < 2; ++t2){
    const unsigned short* ap = Alds + (wv*16 + c0)*72 + t2*32 + g*8;
    bf16x8 a = *(const bf16x8*)ap;
    #pragma unroll
    for (int nf = 0; nf < 3; ++nf){
      bf16x8 b = *(const bf16x8*)(wt2 + (nf*16 + c0)*64 + t2*32 + g*8);
      acc[nf] = __builtin_amdgcn_mfma_f32_16x16x32_bf16(a, b, acc[nf], 0,0,0);
    }
  }
  float aws[3], awd[3];
  aws[0] = aw_s[c0];      awd[0] = aw_d[c0];
  aws[1] = aw_s[16 + c0]; awd[1] = aw_d[16 + c0];
  aws[2] = (c0 < 8) ? aw_s[32 + c0] : 0.f;
  awd[2] = (c0 < 8) ? aw_d[32 + c0] : 0.f;
  #pragma unroll
  for (int i = 0; i < 4; ++i){
    int row = rowbase + wv*16 + 4*g + i;
    float ss = 0.f, dd = 0.f;
    #pragma unroll
    for (int nf = 0; nf < 3; ++nf){
      int col = nf*16 + c0;
      float av = acc[nf][i];
      if (row < N && col < 40) h2x[(size_t)row*64 + 4 + col] = f2e4m3(av);
      float m = (col < 40) ? av : 0.f;
      ss = fmaf(m, aws[nf], ss);
      dd = fmaf(m, awd[nf], dd);
    }
    ss += __shfl_xor(ss, 1); ss += __shfl_xor(ss, 2);
    ss += __shfl_xor(ss, 4); ss += __shfl_xor(ss, 8);
    dd += __shfl_xor(dd, 1); dd += __shfl_xor(dd, 2);
    dd += __shfl_xor(dd, 4); dd += __shfl_xor(dd, 8);
    if (row < N && c0 == 0){
      *(float*)(h2x + (size_t)row*64) = ss;
      ad2[row] = dd;
    }
  }
}

// ---------------- layer-2 aggregation: prefetch-all (max MLP) + log_softmax ----------------
// lane groups of 11: il=0 reads as2 (f32), il=1..10 read u32 of 4 fp8 feats; 5 edges/chunk.
__global__ __launch_bounds__(256) void l2agg_kernel(
    const int* __restrict__ rowstart, const int* __restrict__ csr,
    const unsigned char* __restrict__ h2x, const float* __restrict__ ad2,
    const float* __restrict__ b2, float* __restrict__ out, int N)
{
  int wid = blockIdx.x*4 + (threadIdx.x >> 6);
  if (wid >= N) return;
  const int lane = threadIdx.x & 63;
  const int eg = lane / 11;             // edge group 0..4 (5 = idle lanes 55-63)
  const int il = lane - eg*11;          // 0 = weight lane, 1..10 = feature u32s
  const bool valid = eg < 5;
  int r0 = rowstart[wid], r1 = rowstart[wid+1];
  int cnt = r1 - r0;
  int cap = cnt < 64 ? cnt : 64;
  int myidx = csr[r0 + (lane < cap ? lane : cap-1)];
  const float adv = ad2[wid];

  float a0 = 0.f, a1 = 0.f, a2 = 0.f, a3 = 0.f, den = 0.f;

  // phase A: issue all row gathers
#define L2LOAD(i) \
  unsigned hv##i = 0; \
  if (5*i < cap){ \
    int slot = 5*i + eg; \
    int slc  = slot < cap ? slot : cap-1; \
    int sj = __shfl(myidx, slc); \
    if (valid) hv##i = *(const unsigned*)(h2x + (size_t)sj*64 + 4*il); \
  }
  L2LOAD(0)  L2LOAD(1)  L2LOAD(2)  L2LOAD(3)  L2LOAD(4)
  L2LOAD(5)  L2LOAD(6)  L2LOAD(7)  L2LOAD(8)  L2LOAD(9)
  L2LOAD(10) L2LOAD(11) L2LOAD(12)
#undef L2LOAD

  // phase B: consume in issue order
#define L2COMP(i) \
  if (5*i < cap){ \
    union { unsigned u; float f; } cv; cv.u = hv##i; \
    float t = cv.f + adv; \
    t = (t > 0.f) ? t : LR_SLOPE*t; \
    float w = __expf(t); \
    if (5*i + eg >= cap || !valid) w = 0.f; \
    if (il == 0) den += w; \
    float wj = __shfl(w, eg*11); \
    a0 = fmaf(wj, __builtin_amdgcn_cvt_f32_fp8(hv##i, 0), a0); \
    a1 = fmaf(wj, __builtin_amdgcn_cvt_f32_fp8(hv##i, 1), a1); \
    a2 = fmaf(wj, __builtin_amdgcn_cvt_f32_fp8(hv##i, 2), a2); \
    a3 = fmaf(wj, __builtin_amdgcn_cvt_f32_fp8(hv##i, 3), a3); \
  }
  L2COMP(0)  L2COMP(1)  L2COMP(2)  L2COMP(3)  L2COMP(4)
  L2COMP(5)  L2COMP(6)  L2COMP(7)  L2COMP(8)  L2COMP(9)
  L2COMP(10) L2COMP(11) L2COMP(12)
#undef L2COMP

  for (int r = r0 + 64; r < r1; ++r){   // degree>64 fallback (rare)
    int sx = csr[r];
    unsigned hv = valid ? *(const unsigned*)(h2x + (size_t)sx*64 + 4*il) : 0u;
    union { unsigned u; float f; } cv; cv.u = hv;
    float t = cv.f + adv;
    t = (t > 0.f) ? t : LR_SLOPE*t;
    float w = __expf(t);
    float wj = __shfl(w, 0);            // lane 0 (eg0,il0) holds the weight
    if (lane == 0) den += wj;
    if (eg == 0){
      a0 = fmaf(wj, __builtin_amdgcn_cvt_f32_fp8(hv, 0), a0);
      a1 = fmaf(wj, __builtin_amdgcn_cvt_f32_fp8(hv, 1), a1);
      a2 = fmaf(wj, __builtin_amdgcn_cvt_f32_fp8(hv, 2), a2);
      a3 = fmaf(wj, __builtin_amdgcn_cvt_f32_fp8(hv, 3), a3);
    }
  }
  // den: only il==0 lanes hold contributions; full-wave xor reduce sums them
  #pragma unroll
  for (int off = 32; off; off >>= 1) den += __shfl_xor(den, off);
  // combine the 5 edge groups per feature position
  float t0 = a0, t1 = a1, t2 = a2, t3 = a3;
  #pragma unroll
  for (int gix = 1; gix < 5; ++gix){
    int src = ((eg + gix) % 5)*11 + il;
    t0 += __shfl(a0, src);
    t1 += __shfl(a1, src);
    t2 += __shfl(a2, src);
    t3 += __shfl(a3, src);
  }
  const bool outl = (eg == 0) && (il >= 1);      // lanes 1..10 own feats 4(il-1)..
  const int fb = (il - 1)*4;
  float rdv = 1.f/den;
  float v0 = outl ? fmaf(t0, rdv, b2[fb])     : -1e30f;
  float v1 = outl ? fmaf(t1, rdv, b2[fb + 1]) : -1e30f;
  float v2 = outl ? fmaf(t2, rdv, b2[fb + 2]) : -1e30f;
  float v3 = outl ? fmaf(t3, rdv, b2[fb + 3]) : -1e30f;
  // log_softmax over the 40 features
  float m = fmaxf(fmaxf(v0, v1), fmaxf(v2, v3));
  #pragma unroll
  for (int off = 32; off; off >>= 1) m = fmaxf(m, __shfl_xor(m, off));
  float sum = outl ? (__expf(v0-m) + __expf(v1-m) + __expf(v2-m) + __expf(v3-m)) : 0.f;
  #pragma unroll
  for (int off = 32; off; off >>= 1) sum += __shfl_xor(sum, off);
  if (outl){
    float ls = m + __logf(sum);
    f32x4 o = { v0 - ls, v1 - ls, v2 - ls, v3 - ls };
    *(f32x4*)(out + (size_t)wid*40 + fb) = o;
  }
}

// ---------------- host ----------------
extern "C" void kernel_launch(void* const* d_in, const int* in_sizes, int n_in,
                              void* d_out, int out_size, void* d_ws, size_t ws_size,
                              hipStream_t stream)
{
  const float* x   = (const float*)d_in[0];
  const int*   ei  = (const int*)d_in[1];
  const float* W1  = (const float*)d_in[2];
  const float* aS1 = (const float*)d_in[3];
  const float* aD1 = (const float*)d_in[4];
  const float* b1  = (const float*)d_in[5];
  const float* W2  = (const float*)d_in[6];
  const float* aS2 = (const float*)d_in[7];
  const float* aD2 = (const float*)d_in[8];
  const float* b2  = (const float*)d_in[9];

  const int N   = in_sizes[0] / 512;
  const int E   = in_sizes[1] / 2;
  const int M   = E + N;
  const int NBK = (N + 511) >> 9;

  char* base = (char*)d_ws;
  size_t off = 0;
  auto alloc = [&](size_t bytes)->char* {
    char* p = base + off;
    off += (bytes + 255) & ~(size_t)255;
    return p;
  };
  unsigned char*  h1p  = (unsigned char*)alloc((size_t)N*64);   // fp8 [N][64]
  unsigned short* g1b  = (unsigned short*)alloc((size_t)N*64*2);
  unsigned short* as1p = (unsigned short*)alloc((size_t)N*8*2); // bf16 [N][8]
  float* ad1      = (float*)alloc((size_t)N*8*4);
  int*   rowstart = (int*)alloc((size_t)(N+1)*4);
  int*   bcnt     = (int*)alloc((size_t)NBKMAX*4);
  int*   csr      = (int*)alloc((size_t)M*4);
  unsigned* bucketed = (unsigned*)alloc((size_t)NBKMAX*BCAP*4); // 12 MB
  unsigned short* wt1 = (unsigned short*)alloc(64*512*2);
  unsigned short* wt2 = (unsigned short*)alloc(48*64*2);
  // aliases: h2x packed [N][64] reuses h1p (same size, h1p dead after l1agg); ad2 reuses ad1.
  unsigned char* h2x = h1p;
  float* ad2 = (float*)ad1;
  float* outp = (float*)d_out;

  prep_w_kernel<<<141, 256, 0, stream>>>(W1, W2, wt1, wt2, bcnt);
  gemm1_kernel<<<(N+63)/64, 256, 0, stream>>>(x, wt1, aS1, aD1, h1p, as1p, ad1, N);
  bucketA_kernel<<<(M+2047)/2048, 256, 0, stream>>>(ei, bcnt, bucketed, E, M, NBK);
  bucketB_kernel<<<NBK, 512, 0, stream>>>(bucketed, bcnt, rowstart, csr, N, M, NBK);
  l1agg_kernel<<<(N+3)/4, 256, 0, stream>>>(rowstart, csr, as1p, ad1, h1p, b1, g1b, N);
  gemm2_kernel<<<(N+63)/64, 256, 0, stream>>>(g1b, wt2, aS2, aD2, h2x, ad2, N);
  l2agg_kernel<<<(N+3)/4, 256, 0, stream>>>(rowstart, csr, h2x, ad2, b2, outp, N);
}